// Round 1
// baseline (225.058 us; speedup 1.0000x reference)
//
#include <hip/hip_runtime.h>
#include <math.h>

#define NN 1024
#define LOGN 10
#define B_C 64
#define L_C 160000
#define T_C 622
#define F_C 513
#define WIN_MIN_C (1024.0f / 20.0f)
#define WIN_MAX_C 1024.0f

// ---------------- Kernel A: per-frame normalized Hann taps ----------------
__global__ __launch_bounds__(256) void win_kernel(
    const float* __restrict__ win_length,
    const float* __restrict__ strides,
    const float* __restrict__ win_pow,
    float* __restrict__ tap)   // [T_C][NN]
{
    const int t = blockIdx.x;
    const int tid = threadIdx.x;

    const float wl = fminf(fmaxf(win_length[0], WIN_MIN_C), WIN_MAX_C);
    const float st = fminf(fmaxf(strides[0], 0.0f), WIN_MAX_C);
    const float wp = win_pow[0];

    // frames[t] = t * st (float cumsum of constant st; exact for st=256)
    const float frame = (float)t * st;
    const float frac = frame - floorf(frame);

    const float hi = ceilf(((float)NN - 1.0f + wl) * 0.5f);
    const float lo = floorf(((float)NN - 1.0f - wl) * 0.5f);
    const float off = (wl - (float)NN + 1.0f) * 0.5f;
    const float inv_wl = 1.0f / wl;
    const float twopi = 6.28318530717958647692f;

    __shared__ float s_tap[NN];
    __shared__ float s_red[256];

    float local = 0.0f;
    for (int n = tid; n < NN; n += 256) {
        float base = (float)n - frac;
        float v = 0.5f - 0.5f * cosf(twopi * (base + off) * inv_wl);
        if (base >= hi || base <= lo) v = 0.0f;
        s_tap[n] = v;
        local += v;
    }
    s_red[tid] = local;
    __syncthreads();
    for (int s = 128; s > 0; s >>= 1) {
        if (tid < s) s_red[tid] += s_red[tid + s];
        __syncthreads();
    }
    const float inv_sum = 1.0f / s_red[0];
    const bool pow_one = (wp == 1.0f);
    for (int n = tid; n < NN; n += 256) {
        float v = s_tap[n] * inv_sum;
        if (!pow_one) v = powf(v, wp);
        tap[t * NN + n] = v;
    }
}

// ------------- Kernel B: gather + taper + 1024-pt FFT + |.| -------------
__global__ __launch_bounds__(256) void fft_kernel(
    const float* __restrict__ x,        // [B_C][L_C]
    const float* __restrict__ strides,
    const float* __restrict__ tap,      // [T_C][NN]
    float* __restrict__ out)            // [B_C][F_C][T_C]
{
    const int blk = blockIdx.x;
    const int t = blk % T_C;
    const int b = blk / T_C;
    const int tid = threadIdx.x;

    const float st = fminf(fmaxf(strides[0], 0.0f), WIN_MAX_C);
    const int idx0 = (int)floorf((float)t * st);

    __shared__ float re[2][NN];
    __shared__ float im[2][NN];

    const float* xb = x + (size_t)b * L_C;
    const float* tp = tap + (size_t)t * NN;

    for (int n = tid; n < NN; n += 256) {
        int ix = idx0 + n;
        float v = (ix >= 0 && ix < L_C) ? xb[ix] : 0.0f;
        re[0][n] = v * tp[n];
        im[0][n] = 0.0f;
    }
    __syncthreads();

    // Stockham autosort radix-2, natural in -> natural out
    int cur = 0;
#pragma unroll
    for (int p = 0; p < LOGN; ++p) {
        const int s = 1 << p;
        const float neg_pi_over_s = -3.14159265358979323846f / (float)s;
        const int nxt = cur ^ 1;
#pragma unroll
        for (int ii = 0; ii < 2; ++ii) {
            const int i = tid + ii * 256;       // i in [0, NN/2)
            const int m = i & (s - 1);
            const int blk2 = i >> p;
            const float ar = re[cur][i];
            const float ai = im[cur][i];
            const float br = re[cur][i + NN / 2];
            const float bi = im[cur][i + NN / 2];
            float sw, cw;
            __sincosf(neg_pi_over_s * (float)m, &sw, &cw);
            const float tr = cw * br - sw * bi;
            const float ti = cw * bi + sw * br;
            const int o = (blk2 << (p + 1)) + m;
            re[nxt][o] = ar + tr;
            im[nxt][o] = ai + ti;
            re[nxt][o + s] = ar - tr;
            im[nxt][o + s] = ai - ti;
        }
        __syncthreads();
        cur = nxt;
    }

    for (int f = tid; f < F_C; f += 256) {
        const float mr = re[cur][f];
        const float mi = im[cur][f];
        out[((size_t)b * F_C + f) * T_C + t] = sqrtf(mr * mr + mi * mi);
    }
}

extern "C" void kernel_launch(void* const* d_in, const int* in_sizes, int n_in,
                              void* d_out, int out_size, void* d_ws, size_t ws_size,
                              hipStream_t stream) {
    const float* x   = (const float*)d_in[0];
    const float* wl  = (const float*)d_in[1];
    const float* st  = (const float*)d_in[2];
    const float* wp  = (const float*)d_in[3];
    float* out = (float*)d_out;
    float* tap = (float*)d_ws;   // T_C*NN floats = ~2.55 MB

    win_kernel<<<dim3(T_C), dim3(256), 0, stream>>>(wl, st, wp, tap);
    fft_kernel<<<dim3(B_C * T_C), dim3(256), 0, stream>>>(x, st, tap, out);
}

// Round 2
// 163.501 us; speedup vs baseline: 1.3765x; 1.3765x over previous
//
#include <hip/hip_runtime.h>
#include <math.h>

#define NN 1024
#define B_C 64
#define L_C 160000
#define T_C 622
#define F_C 513
#define TT 16                 // frames per block tile
#define NPAIR (TT / 2)
#define WIN_MIN_C (1024.0f / 20.0f)
#define WIN_MAX_C 1024.0f
#define PI_F 3.14159265358979323846f
// LDS pad remap: +1 float per 32 → breaks power-of-2 stride bank conflicts
#define P(a) ((a) + ((a) >> 5))

// ---------------- Kernel A: per-frame normalized Hann taps ----------------
__global__ __launch_bounds__(256) void win_kernel(
    const float* __restrict__ win_length,
    const float* __restrict__ strides,
    const float* __restrict__ win_pow,
    float* __restrict__ tap)   // [T_C][NN]
{
    const int t = blockIdx.x;
    const int tid = threadIdx.x;

    const float wl = fminf(fmaxf(win_length[0], WIN_MIN_C), WIN_MAX_C);
    const float st = fminf(fmaxf(strides[0], 0.0f), WIN_MAX_C);
    const float wp = win_pow[0];

    const float frame = (float)t * st;
    const float frac = frame - floorf(frame);

    const float hi = ceilf(((float)NN - 1.0f + wl) * 0.5f);
    const float lo = floorf(((float)NN - 1.0f - wl) * 0.5f);
    const float off = (wl - (float)NN + 1.0f) * 0.5f;
    const float inv_wl = 1.0f / wl;
    const float twopi = 6.28318530717958647692f;

    __shared__ float s_tap[NN];
    __shared__ float s_red[256];

    float local = 0.0f;
    for (int n = tid; n < NN; n += 256) {
        float base = (float)n - frac;
        float v = 0.5f - 0.5f * cosf(twopi * (base + off) * inv_wl);
        if (base >= hi || base <= lo) v = 0.0f;
        s_tap[n] = v;
        local += v;
    }
    s_red[tid] = local;
    __syncthreads();
    for (int s = 128; s > 0; s >>= 1) {
        if (tid < s) s_red[tid] += s_red[tid + s];
        __syncthreads();
    }
    const float inv_sum = 1.0f / s_red[0];
    const bool pow_one = (wp == 1.0f);
    for (int n = tid; n < NN; n += 256) {
        float v = s_tap[n] * inv_sum;
        if (!pow_one) v = powf(v, wp);
        tap[t * NN + n] = v;
    }
}

// ---- Kernel B: 16 frames/block, pair-packed radix-4 Stockham FFT + |.| ----
__global__ __launch_bounds__(256) void fft16_kernel(
    const float* __restrict__ x,        // [B_C][L_C]
    const float* __restrict__ strides,
    const float* __restrict__ tap,      // [T_C][NN]
    float* __restrict__ out)            // [B_C][F_C][T_C]
{
    const int ntile = (T_C + TT - 1) / TT;   // 39
    const int tile = blockIdx.x % ntile;
    const int b = blockIdx.x / ntile;
    const int t0 = tile * TT;
    const int tid = threadIdx.x;

    const float st = fminf(fmaxf(strides[0], 0.0f), WIN_MAX_C);

    __shared__ float re[2][NN + (NN >> 5)];
    __shared__ float im[2][NN + (NN >> 5)];
    __shared__ float mag[F_C][TT + 1];

    const float* xb = x + (size_t)b * L_C;

    for (int j = 0; j < NPAIR; ++j) {
        const int tA = t0 + 2 * j;
        const int tB = tA + 1;
        if (tA >= T_C) break;
        const bool hasB = (tB < T_C);
        const int idxA = (int)floorf((float)tA * st);
        const int idxB = (int)floorf((float)tB * st);
        const float* tpA = tap + (size_t)tA * NN;
        const float* tpB = tap + (size_t)tB * NN;

        // load + taper: frame A -> re, frame B -> im (packed complex)
        for (int n = tid; n < NN; n += 256) {
            int ia = idxA + n;
            float va = (ia >= 0 && ia < L_C) ? xb[ia] * tpA[n] : 0.0f;
            float vb = 0.0f;
            if (hasB) {
                int ib = idxB + n;
                vb = (ib >= 0 && ib < L_C) ? xb[ib] * tpB[n] : 0.0f;
            }
            re[0][P(n)] = va;
            im[0][P(n)] = vb;
        }
        __syncthreads();

        // 5 radix-4 Stockham stages, natural order in/out
        int cur = 0;
#pragma unroll
        for (int p = 0; p < 5; ++p) {
            const int s = 1 << (2 * p);
            const int nxt = cur ^ 1;
            const int i = tid;                 // exactly N/4 = 256 butterflies
            const int m = i & (s - 1);
            const int g = i >> (2 * p);

            float a0r = re[cur][P(i)],       a0i = im[cur][P(i)];
            float a1r = re[cur][P(i + 256)], a1i = im[cur][P(i + 256)];
            float a2r = re[cur][P(i + 512)], a2i = im[cur][P(i + 512)];
            float a3r = re[cur][P(i + 768)], a3i = im[cur][P(i + 768)];

            const float ang = -(PI_F * 0.5f / (float)s) * (float)m;
            float s1, c1;
            __sincosf(ang, &s1, &c1);
            float c2 = c1 * c1 - s1 * s1, s2 = 2.0f * c1 * s1;
            float c3 = c1 * c2 - s1 * s2, s3 = c1 * s2 + s1 * c2;

            float t1r = c1 * a1r - s1 * a1i, t1i = c1 * a1i + s1 * a1r;
            float t2r = c2 * a2r - s2 * a2i, t2i = c2 * a2i + s2 * a2r;
            float t3r = c3 * a3r - s3 * a3i, t3i = c3 * a3i + s3 * a3r;

            float s02r = a0r + t2r, s02i = a0i + t2i;
            float d02r = a0r - t2r, d02i = a0i - t2i;
            float s13r = t1r + t3r, s13i = t1i + t3i;
            float d13r = t1r - t3r, d13i = t1i - t3i;

            const int o = (g << (2 * p + 2)) + m;
            re[nxt][P(o)]         = s02r + s13r;  im[nxt][P(o)]         = s02i + s13i;
            re[nxt][P(o + s)]     = d02r + d13i;  im[nxt][P(o + s)]     = d02i - d13r;
            re[nxt][P(o + 2 * s)] = s02r - s13r;  im[nxt][P(o + 2 * s)] = s02i - s13i;
            re[nxt][P(o + 3 * s)] = d02r - d13i;  im[nxt][P(o + 3 * s)] = d02i + d13r;
            __syncthreads();
            cur = nxt;
        }

        // unpack the two real spectra + magnitude, stage into mag[][]
        for (int k = tid; k < F_C; k += 256) {
            int nk = (NN - k) & (NN - 1);
            float zr = re[cur][P(k)],  zi = im[cur][P(k)];
            float yr = re[cur][P(nk)], yi = im[cur][P(nk)];
            float xar = 0.5f * (zr + yr), xai = 0.5f * (zi - yi);
            float xbr = 0.5f * (zi + yi), xbi = 0.5f * (yr - zr);
            mag[k][2 * j] = sqrtf(xar * xar + xai * xai);
            if (hasB) mag[k][2 * j + 1] = sqrtf(xbr * xbr + xbi * xbi);
        }
        __syncthreads();
    }

    // coalesced write: rows of 16 consecutive t per f
    for (int e = tid; e < F_C * TT; e += 256) {
        int f = e >> 4;
        int tt = e & (TT - 1);
        int t = t0 + tt;
        if (t < T_C)
            out[((size_t)b * F_C + f) * T_C + t] = mag[f][tt];
    }
}

extern "C" void kernel_launch(void* const* d_in, const int* in_sizes, int n_in,
                              void* d_out, int out_size, void* d_ws, size_t ws_size,
                              hipStream_t stream) {
    const float* x   = (const float*)d_in[0];
    const float* wl  = (const float*)d_in[1];
    const float* st  = (const float*)d_in[2];
    const float* wp  = (const float*)d_in[3];
    float* out = (float*)d_out;
    float* tap = (float*)d_ws;   // T_C*NN floats ~ 2.55 MB

    const int ntile = (T_C + TT - 1) / TT;   // 39
    win_kernel<<<dim3(T_C), dim3(256), 0, stream>>>(wl, st, wp, tap);
    fft16_kernel<<<dim3(B_C * ntile), dim3(256), 0, stream>>>(x, st, tap, out);
}